// Round 3
// baseline (298.623 us; speedup 1.0000x reference)
//
#include <hip/hip_runtime.h>

// SoftDepthShader: softmax depth blend, N=8 H=256 W=256 K=50 (524288 pixels).
// ~315 MB read, ~2 MB write -> memory-bound.
//
// R3/R5 post-mortem: three kernel structures all pin at ~110 us, 1.45 TB/s
// HBM, VALUBusy 25%, VGPR<=28. Source-level load-phase separation (R5:
// sched_barrier + launch_bounds) was defeated by RA (28 VGPRs proves loads
// serialized). Also every team wave-load is 8 scattered 64B segments
// straddling 128B lines (pixel stride 200B) -> poor L1/L2/HBM efficiency.
//
// R6 = catalog-minimal 2-phase LDS pipeline (T3-min, proven on GEMM m97):
//   - Tile = 128 pixels. Per array per tile: 25,600 B = exactly 25 x 1024 B
//     wave-steps. Staging via __builtin_amdgcn_global_load_lds width=16:
//     perfectly linear 128B-aligned streams, NO dest VGPRs -> in-flight
//     bytes (76.8 KB/block) decoupled from the register allocator.
//   - Double-buffered LDS (2 x 76,800 B = 153,600 B; gfx950 allows up to
//     160 KB/block -- HK attn uses 160 KB). Prefetch tile t+1 during
//     compute of tile t; raw s_barrier + asm vmcnt(0) at iteration end
//     (exactly one stage outstanding at the drain).
//   - Compute = R5's harness-proven pixel_blend, reading LDS (float2 team
//     chunks {q, q+8, q+16} + tail chunk 24 gated to lane q==0).
//   - 256 blocks x 512 threads (8 waves), 1 block/CU (LDS-limited), 16
//     tiles per block, contiguous streaming per block.

constexpr int THREADS = 512;
constexpr int WAVES   = THREADS / 64;       // 8
constexpr int TILE_PX = 128;
constexpr int PX_B    = 200;                // bytes per pixel per array
constexpr int ARR_B   = TILE_PX * PX_B;     // 25600 = 25 x 1024
constexpr int BUF_B   = 3 * ARR_B;          // 76800
constexpr int ASTEPS  = ARR_B / 1024;       // 25 wave-steps per array
constexpr int STEPS   = 3 * ASTEPS;         // 75 wave-steps per tile
constexpr int NBLOCKS = 256;

constexpr float INV_SIGMA  = 1e4f;          // 1/sigma
constexpr float INVG       = 1e4f;          // 1/gamma
constexpr float ZFAR       = 100.0f;
constexpr float ZRANGE     = 99.0f;         // zfar - znear
constexpr float INV_ZRANGE = 1.0f / 99.0f;
constexpr float EPS        = 1e-10f;

#define GLDS16(gp, lp) __builtin_amdgcn_global_load_lds(                     \
    (const __attribute__((address_space(1))) void*)(gp),                     \
    (__attribute__((address_space(3))) void*)(lp), 16, 0, 0)

// R5's harness-proven per-pixel pipeline, verbatim.
__device__ __forceinline__ void pixel_blend(
    const int2 fa, const int2 fb, const int2 fc, const int2 fd,
    const float2 za, const float2 zb, const float2 zc, const float2 zd,
    const float2 da, const float2 db, const float2 dc, const float2 dd,
    const bool tail_owner,
    float& m_out, float& s1_out, float& s2_out)
{
    const bool m0 = (fa.x >= 0),               m1 = (fa.y >= 0);
    const bool m2 = (fb.x >= 0),               m3 = (fb.y >= 0);
    const bool m4 = (fc.x >= 0),               m5 = (fc.y >= 0);
    const bool m6 = tail_owner && (fd.x >= 0), m7 = tail_owner && (fd.y >= 0);

    float zv[8], pv[8];
    zv[0] = m0 ? (ZFAR - za.x) * INV_ZRANGE : 0.0f;
    zv[1] = m1 ? (ZFAR - za.y) * INV_ZRANGE : 0.0f;
    zv[2] = m2 ? (ZFAR - zb.x) * INV_ZRANGE : 0.0f;
    zv[3] = m3 ? (ZFAR - zb.y) * INV_ZRANGE : 0.0f;
    zv[4] = m4 ? (ZFAR - zc.x) * INV_ZRANGE : 0.0f;
    zv[5] = m5 ? (ZFAR - zc.y) * INV_ZRANGE : 0.0f;
    zv[6] = m6 ? (ZFAR - zd.x) * INV_ZRANGE : 0.0f;
    zv[7] = m7 ? (ZFAR - zd.y) * INV_ZRANGE : 0.0f;
    pv[0] = m0 ? 1.0f / (1.0f + __expf(da.x * INV_SIGMA)) : 0.0f;
    pv[1] = m1 ? 1.0f / (1.0f + __expf(da.y * INV_SIGMA)) : 0.0f;
    pv[2] = m2 ? 1.0f / (1.0f + __expf(db.x * INV_SIGMA)) : 0.0f;
    pv[3] = m3 ? 1.0f / (1.0f + __expf(db.y * INV_SIGMA)) : 0.0f;
    pv[4] = m4 ? 1.0f / (1.0f + __expf(dc.x * INV_SIGMA)) : 0.0f;
    pv[5] = m5 ? 1.0f / (1.0f + __expf(dc.y * INV_SIGMA)) : 0.0f;
    pv[6] = m6 ? 1.0f / (1.0f + __expf(dd.x * INV_SIGMA)) : 0.0f;
    pv[7] = m7 ? 1.0f / (1.0f + __expf(dd.y * INV_SIGMA)) : 0.0f;

    float m = fmaxf(fmaxf(fmaxf(zv[0], zv[1]), fmaxf(zv[2], zv[3])),
                    fmaxf(fmaxf(zv[4], zv[5]), fmaxf(zv[6], zv[7])));
    m = fmaxf(m, __shfl_xor(m, 1));
    m = fmaxf(m, __shfl_xor(m, 2));
    m = fmaxf(m, __shfl_xor(m, 4));
    m = fmaxf(m, EPS);

    float S1a = 0.0f, S1b = 0.0f, S2a = 0.0f, S2b = 0.0f;
    #pragma unroll
    for (int j = 0; j < 8; j += 2) {
        const float w0 = pv[j]   * __expf((zv[j]   - m) * INVG);
        const float w1 = pv[j+1] * __expf((zv[j+1] - m) * INVG);
        S1a += w0;
        S1b += w1;
        S2a += w0 * (ZFAR - zv[j]   * ZRANGE);
        S2b += w1 * (ZFAR - zv[j+1] * ZRANGE);
    }
    float S1 = S1a + S1b;
    float S2 = S2a + S2b;
    S1 += __shfl_xor(S1, 1);  S1 += __shfl_xor(S1, 2);  S1 += __shfl_xor(S1, 4);
    S2 += __shfl_xor(S2, 1);  S2 += __shfl_xor(S2, 2);  S2 += __shfl_xor(S2, 4);

    m_out = m;  s1_out = S1;  s2_out = S2;
}

__global__ __launch_bounds__(THREADS, 1) void soft_depth_kernel(
    const float* __restrict__ zbuf,
    const float* __restrict__ dists,
    const int*   __restrict__ p2f,
    float*       __restrict__ out,
    const int tiles_per_block)
{
    __shared__ __align__(16) char smem[2 * BUF_B];   // 153,600 B

    const int t    = threadIdx.x;
    const int lane = t & 63;
    const int wid  = t >> 6;
    const int q    = t & 7;
    const int team = t >> 3;                 // 0..63 -> 2 pixels each

    const char* __restrict__ zc = (const char*)zbuf;
    const char* __restrict__ dc = (const char*)dists;
    const char* __restrict__ fc = (const char*)p2f;

    const int tile0 = blockIdx.x * tiles_per_block;

    // ---- stage one tile (wave-steps round-robin; all steps full-wave) ----
    auto stage = [&](int tile, char* buf) {
        const size_t tb = (size_t)tile * ARR_B;
        const char* zt = zc + tb;
        const char* dt = dc + tb;
        const char* ft = fc + tb;
        for (int s = wid; s < STEPS; s += WAVES) {          // wave-uniform
            const int a = s / ASTEPS;                        // 0..2
            const int j = s - a * ASTEPS;                    // 0..24
            const char* g = (a == 0) ? zt : (a == 1) ? dt : ft;
            GLDS16(g + j * 1024 + lane * 16, buf + a * ARR_B + j * 1024);
        }
    };

    // ---- compute one tile from LDS (R5 team structure) ----
    auto compute = [&](int tile, const char* buf) {
        const float2* __restrict__ zl = (const float2*)(buf);
        const float2* __restrict__ dl = (const float2*)(buf + ARR_B);
        const int2*   __restrict__ fl = (const int2*)(buf + 2 * ARR_B);

        const int pA  = 2 * team;
        const int cbA = pA * 25;             // float2 chunks per pixel = 25
        const int cbB = cbA + 25;
        const int a0 = cbA + q, a1 = cbA + q + 8, a2 = cbA + q + 16, a3 = cbA + 24;
        const int b0 = cbB + q, b1 = cbB + q + 8, b2 = cbB + q + 16, b3 = cbB + 24;

        const int2   fA0 = fl[a0], fA1 = fl[a1], fA2 = fl[a2], fA3 = fl[a3];
        const int2   fB0 = fl[b0], fB1 = fl[b1], fB2 = fl[b2], fB3 = fl[b3];
        const float2 zA0 = zl[a0], zA1 = zl[a1], zA2 = zl[a2], zA3 = zl[a3];
        const float2 zB0 = zl[b0], zB1 = zl[b1], zB2 = zl[b2], zB3 = zl[b3];
        const float2 dA0 = dl[a0], dA1 = dl[a1], dA2 = dl[a2], dA3 = dl[a3];
        const float2 dB0 = dl[b0], dB1 = dl[b1], dB2 = dl[b2], dB3 = dl[b3];

        const bool town = (q == 0);
        float mA, S1A, S2A, mB, S1B, S2B;
        pixel_blend(fA0, fA1, fA2, fA3, zA0, zA1, zA2, zA3,
                    dA0, dA1, dA2, dA3, town, mA, S1A, S2A);
        pixel_blend(fB0, fB1, fB2, fB3, zB0, zB1, zB2, zB3,
                    dB0, dB1, dB2, dB3, town, mB, S1B, S2B);

        if (q < 2) {
            const float m  = (q == 0) ? mA  : mB;
            const float s1 = (q == 0) ? S1A : S1B;
            const float s2 = (q == 0) ? S2A : S2B;
            const float delta = fmaxf(__expf((EPS - m) * INVG), EPS);
            out[(size_t)tile * TILE_PX + pA + q] = (s2 + delta) / (s1 + delta);
        }
    };

    // ---- 2-phase pipeline: STAGE(next) || compute(cur); drain at end ----
    int cur = 0;
    stage(tile0, smem);
    asm volatile("s_waitcnt vmcnt(0)" ::: "memory");
    __builtin_amdgcn_s_barrier();
    __builtin_amdgcn_sched_barrier(0);

    for (int i = 0; i < tiles_per_block; ++i) {
        if (i + 1 < tiles_per_block)
            stage(tile0 + i + 1, smem + (cur ^ 1) * BUF_B);  // prefetch in flight
        __builtin_amdgcn_sched_barrier(0);
        compute(tile0 + i, smem + cur * BUF_B);              // overlaps delivery
        asm volatile("s_waitcnt vmcnt(0)" ::: "memory");     // drain prefetch
        __builtin_amdgcn_s_barrier();
        __builtin_amdgcn_sched_barrier(0);
        cur ^= 1;
    }
}

extern "C" void kernel_launch(void* const* d_in, const int* in_sizes, int n_in,
                              void* d_out, int out_size, void* d_ws, size_t ws_size,
                              hipStream_t stream) {
    const float* zbuf  = (const float*)d_in[0];
    const float* dists = (const float*)d_in[1];
    const int*   p2f   = (const int*)d_in[2];
    float* out = (float*)d_out;

    const int pixels = out_size;                   // 524288
    const int tiles  = pixels / TILE_PX;           // 4096
    const int tpb    = tiles / NBLOCKS;            // 16 (exact)

    soft_depth_kernel<<<dim3(NBLOCKS), dim3(THREADS), 0, stream>>>(
        zbuf, dists, p2f, out, tpb);
}